// Round 2
// baseline (306.867 us; speedup 1.0000x reference)
//
#include <hip/hip_runtime.h>
#include <hip/hip_bf16.h>

#define NNODES 100000
#define NEDGES 1600000
#define INC 128
#define HIDC 64
#define BSHIFT 8                      // 256 nodes per bucket
#define NB ((NNODES + 255) / 256)     // 391 buckets
#define TILE 8192                     // edges per fill1 workgroup (32/thread)
#define HSLOTS 8192                   // LDS hash slots in fill2 (32 KB)
#define CAP 8192                      // staging words per bucket (avg load ~4092)
#define CAPE 8192                     // csr words per bucket (rows padded to x8)
#define NBLK_FILL ((NEDGES + TILE - 1) / TILE)   // 196
#define NBLK_LIN ((NNODES + 63) / 64)            // 1563

typedef short bf16x8 __attribute__((ext_vector_type(8)));
typedef float f32x4 __attribute__((ext_vector_type(4)));

__device__ __forceinline__ float bf2f(unsigned short h) {
    return __uint_as_float((unsigned)h << 16);
}
__device__ __forceinline__ unsigned short f2bf(float f) {
    __hip_bfloat16 h = __float2bfloat16(f);
    return *(unsigned short*)&h;
}

// ---- prep kernel: w1 -> transposed bf16 hi/lo split; w44/bias4 fold; sentinel ----
__global__ __launch_bounds__(256) void prep_w_kernel(
        const float* __restrict__ w1, unsigned short* __restrict__ wTh,
        unsigned short* __restrict__ wTl,
        const float* __restrict__ w2_lin, const float* __restrict__ b2,
        const float* __restrict__ wc, float* __restrict__ w44,
        float* __restrict__ bias4, unsigned short* __restrict__ out) {
    int t = threadIdx.x;
    int e = blockIdx.x * 256 + t;            // 0..8191 over wT[64][128]
    int c = e >> 7, k = e & 127;
    float v = w1[k * 64 + c];
    unsigned short hi = f2bf(v);
    wTh[e] = hi;
    wTl[e] = f2bf(v - bf2f(hi));
    if (blockIdx.x == 0) {
        if (t < 16)   // zero sentinel row for padded gathers
            *(ushort4*)(out + (size_t)NNODES * 64 + t * 4) = make_ushort4(0, 0, 0, 0);
        int kk = t >> 2, j = t & 3;
        float a = 0.0f;
#pragma unroll 8
        for (int i = 0; i < 64; i++) {
            float w4 = (j < 2) ? wc[i * 2 + j] : wc[(64 + i) * 2 + (j - 2)];
            a += w2_lin[kk * 64 + i] * w4;
        }
        w44[kk * 4 + j] = a;
        if (kk == 0) {
            float bb4 = 0.0f;
            for (int i = 0; i < 64; i++) {
                float w4 = (j < 2) ? wc[i * 2 + j] : wc[(64 + i) * 2 + (j - 2)];
                bb4 += b2[i] * w4;
            }
            bias4[j] = bb4;
        }
    }
}

// ---- fat kernel: fill1 binning (blocks [0, NBLK_FILL)) + MFMA lin1 GEMM (rest) ----
// GEMM is bf16x3 error-compensated: x = xh+xl, w = wh+wl (bf16 each);
// h = xh*wh + xh*wl + xl*wh  (xl*wl term ~2^-18 rel, dropped).
__global__ __launch_bounds__(256) void fat_kernel(
        const float* __restrict__ x,
        const unsigned short* __restrict__ wTh, const unsigned short* __restrict__ wTl,
        const float* __restrict__ b, unsigned short* __restrict__ out,
        const int* __restrict__ src, const int* __restrict__ dst,
        int* __restrict__ bucket_fill, unsigned int* __restrict__ staging) {
    __shared__ alignas(16) unsigned short s_a[2][64 * 128];  // x hi/lo, 32 KB, swizzled
    __shared__ alignas(16) unsigned short s_b[2][64 * 128];  // wT hi/lo, 32 KB, swizzled
    int t = threadIdx.x;
    if (blockIdx.x < NBLK_FILL) {
        // ---------------- fill1 branch ----------------
        int* cnt = (int*)&s_a[0][0];
        int* basepos = cnt + NB;
        unsigned int* svl = (unsigned int*)&s_b[0][0];   // 8192 words = TILE
        for (int i = t; i < NB; i += 256) cnt[i] = 0;
        __syncthreads();
        int tile0 = blockIdx.x * TILE;
        int meta[32];
#pragma unroll
        for (int i = 0; i < 32; i++) {
            int e = tile0 + i * 256 + t;
            meta[i] = -1;
            if (e < NEDGES) {
                int s = src[e], d = dst[e];
                int bkt = d >> BSHIFT;
                int r = atomicAdd(&cnt[bkt], 1);     // < TILE = 8192 (13 bits)
                meta[i] = (bkt << 13) | r;
                svl[i * 256 + t] = ((unsigned)(d & 255) << 17) | (unsigned)s;
            }
        }
        __syncthreads();
        for (int i = t; i < NB; i += 256) {
            int c = cnt[i];
            int g = (c > 0) ? atomicAdd(&bucket_fill[i], c) : 0;
            basepos[i] = (i << 13) + g;              // staging region = [i*CAP, ...)
        }
        __syncthreads();
#pragma unroll
        for (int i = 0; i < 32; i++) {
            if (meta[i] >= 0) {
                int bkt = meta[i] >> 13, r = meta[i] & 8191;
                staging[basepos[bkt] + r] = svl[i * 256 + t];
            }
        }
    } else {
        // ---------------- MFMA GEMM branch: 64 nodes x 64 cols, K=128 ----------------
        int node0 = (blockIdx.x - NBLK_FILL) * 64;
        float4 vx[8];
#pragma unroll
        for (int it = 0; it < 8; it++) {
            int idx = it * 256 + t;                  // 0..2047 float4s of x tile
            int row = idx >> 5, c4 = idx & 31;
            int node = node0 + row;
            if (node < NNODES)
                vx[it] = *(const float4*)(x + (size_t)node * INC + c4 * 4);
            else
                vx[it] = make_float4(0.f, 0.f, 0.f, 0.f);
        }
        uint4 vwh[4], vwl[4];
#pragma unroll
        for (int j = 0; j < 4; j++) {
            vwh[j] = *(const uint4*)(wTh + (size_t)(j * 256 + t) * 8);
            vwl[j] = *(const uint4*)(wTl + (size_t)(j * 256 + t) * 8);
        }
        // convert x -> bf16 hi/lo, write LDS swizzled (k ^= (row&7)<<3, elem units)
#pragma unroll
        for (int it = 0; it < 8; it++) {
            int idx = it * 256 + t;
            int row = idx >> 5, c4 = idx & 31;
            ushort4 hi, lo;
            hi.x = f2bf(vx[it].x); lo.x = f2bf(vx[it].x - bf2f(hi.x));
            hi.y = f2bf(vx[it].y); lo.y = f2bf(vx[it].y - bf2f(hi.y));
            hi.z = f2bf(vx[it].z); lo.z = f2bf(vx[it].z - bf2f(hi.z));
            hi.w = f2bf(vx[it].w); lo.w = f2bf(vx[it].w - bf2f(hi.w));
            int ke = (c4 * 4) ^ ((row & 7) << 3);
            *(ushort4*)&s_a[0][row * 128 + ke] = hi;
            *(ushort4*)&s_a[1][row * 128 + ke] = lo;
        }
#pragma unroll
        for (int j = 0; j < 4; j++) {
            int idx = j * 256 + t;                   // ushort8 chunk of wT[64][128]
            int col = idx >> 4, k0 = (idx & 15) * 8;
            int ke = k0 ^ ((col & 7) << 3);
            *(uint4*)&s_b[0][col * 128 + ke] = vwh[j];
            *(uint4*)&s_b[1][col * 128 + ke] = vwl[j];
        }
        __syncthreads();
        int l = t & 63, wv = t >> 6;
        int mr = l & 15, g = l >> 4;
        int arow = wv * 16 + mr;                     // arow&7 == mr&7 (wv*16 % 8 == 0)
        f32x4 acc[4] = {{0.f, 0.f, 0.f, 0.f}, {0.f, 0.f, 0.f, 0.f},
                        {0.f, 0.f, 0.f, 0.f}, {0.f, 0.f, 0.f, 0.f}};
#pragma unroll
        for (int ks = 0; ks < 4; ks++) {
            int k0 = ks * 32 + g * 8;
            int ko = k0 ^ ((mr & 7) << 3);
            bf16x8 ah = *(const bf16x8*)&s_a[0][arow * 128 + ko];
            bf16x8 al = *(const bf16x8*)&s_a[1][arow * 128 + ko];
#pragma unroll
            for (int cb = 0; cb < 4; cb++) {
                int bo = (cb * 16 + mr) * 128 + ko;
                bf16x8 bh = *(const bf16x8*)&s_b[0][bo];
                bf16x8 bl = *(const bf16x8*)&s_b[1][bo];
                acc[cb] = __builtin_amdgcn_mfma_f32_16x16x32_bf16(ah, bh, acc[cb], 0, 0, 0);
                acc[cb] = __builtin_amdgcn_mfma_f32_16x16x32_bf16(ah, bl, acc[cb], 0, 0, 0);
                acc[cb] = __builtin_amdgcn_mfma_f32_16x16x32_bf16(al, bh, acc[cb], 0, 0, 0);
            }
        }
#pragma unroll
        for (int cb = 0; cb < 4; cb++) {
            int col = cb * 16 + mr;
            float bb = b[col];
#pragma unroll
            for (int r = 0; r < 4; r++) {
                int node = node0 + wv * 16 + g * 4 + r;
                if (node < NNODES)
                    out[(size_t)node * 64 + col] = f2bf(acc[cb][r] + bb);
            }
        }
    }
}

// fill pass 2: one WG per 256-node bucket, fixed csr region [b*CAPE, ...).
// Rows padded to x8 with sentinel n_nodes (points at the zero row).
__global__ __launch_bounds__(256) void fill2_kernel(
        const int* __restrict__ bucket_fill, const unsigned int* __restrict__ staging,
        int* __restrict__ csr_src, int* __restrict__ row_start,
        int* __restrict__ row_pdeg, float* __restrict__ norm, int n_nodes) {
    __shared__ int cnt[256];
    __shared__ int dcount[256];
    __shared__ int off[256];
    __shared__ int pscan[256];
    __shared__ unsigned short rank16[CAP];   // 16 KB
    __shared__ unsigned int ht[HSLOTS];      // 32 KB
    int t = threadIdx.x;
    int b = blockIdx.x;
    int node0 = b << BSHIFT;
    int nn = min(256, n_nodes - node0);
    cnt[t] = 0; dcount[t] = 0;
    {
        uint4* h4 = (uint4*)ht;
        uint4 ff = make_uint4(0xFFFFFFFFu, 0xFFFFFFFFu, 0xFFFFFFFFu, 0xFFFFFFFFu);
        for (int i = t; i < HSLOTS / 4; i += 256) h4[i] = ff;
    }
    __syncthreads();
    int start = b << 13;
    int total = bucket_fill[b];
    // phase A: count + rank + dedup
    for (int li = t; li < total; li += 256) {
        unsigned int w = staging[start + li];
        int s = (int)(w & 0x1FFFFu);
        int dl = (int)(w >> 17);
        int r = atomicAdd(&cnt[dl], 1);
        rank16[li] = (unsigned short)r;
        if (s != node0 + dl) {  // self-loops merge with the I-diagonal
            unsigned int slot = ((w * 2654435761u) >> 13) & (HSLOTS - 1);
            while (true) {
                unsigned int prev = atomicCAS(&ht[slot], 0xFFFFFFFFu, w);
                if (prev == 0xFFFFFFFFu) { atomicAdd(&dcount[dl], 1); break; }
                if (prev == w) break;
                slot = (slot + 1) & (HSLOTS - 1);
            }
        }
    }
    __syncthreads();
    // exclusive prefix of x8-padded counts -> csr offsets within [b*CAPE, ...)
    int cv = cnt[t];
    int pv = (cv + 7) & ~7;
    pscan[t] = pv;
    __syncthreads();
    for (int o = 1; o < 256; o <<= 1) {
        int xx = (t >= o) ? pscan[t - o] : 0;
        __syncthreads();
        pscan[t] += xx;
        __syncthreads();
    }
    off[t] = b * CAPE + pscan[t] - pv;
    __syncthreads();
    if (t < nn) {
        row_start[node0 + t] = off[t];
        row_pdeg[node0 + t] = pv;
        norm[node0 + t] = 1.0f / (1.0f + (float)dcount[t]);
    }
    // sentinel-pad the tail of each row
    for (int k = cv; k < pv; k++) csr_src[off[t] + k] = n_nodes;
    // phase B: scatter csr
    for (int li = t; li < total; li += 256) {
        unsigned int w = staging[start + li];
        int s = (int)(w & 0x1FFFFu);
        int dl = (int)(w >> 17);
        csr_src[off[dl] + (int)rank16[li]] = s;
    }
}

// One wave per node; dwordx4 gathers: one wave-load = 64 lanes x 16 B = 8 full
// h1 rows (8 edges). Lane role: q = lane>>3 selects the edge slot, d4 = lane&7
// selects which 16 B (8 channels) of the row. Source index broadcast via one
// ds_bpermute (__shfl) per load -- no readlane/cndmask chains. Up to 8 loads
// per 64-edge chunk issued back-to-back under wave-uniform ns branches for MLP.
// Fused PAN combine + relu + rank-4 projection -> u. h1 never hits global mem.
__global__ void agg_h_kernel(const unsigned int* __restrict__ lin32,
                             const int* __restrict__ row_start,
                             const int* __restrict__ row_pdeg,
                             const int* __restrict__ csr_src,
                             const float* __restrict__ norm,
                             const float* __restrict__ wpan, const float* __restrict__ w44,
                             const float* __restrict__ bias4, float* __restrict__ u,
                             int n_nodes) {
    int t = threadIdx.x;
    int node = blockIdx.x * 4 + (t >> 6);
    int lane = t & 63;
    int q = lane >> 3;       // edge slot within a group of 8
    int d4 = lane & 7;       // which dwordx4 of the 128-B row
    if (blockIdx.x == 0 && t < 4) u[n_nodes * 4 + t] = 0.0f;  // zero row for agg_pq4 pads
    if (node >= n_nodes) return;
    int e0 = row_start[node];
    int pd = row_pdeg[node];                 // multiple of 8
    const uint4* rb = (const uint4*)lin32;   // row = 8 uint4
    float aL0 = 0.f, aH0 = 0.f, aL1 = 0.f, aH1 = 0.f;
    float aL2 = 0.f, aH2 = 0.f, aL3 = 0.f, aH3 = 0.f;
#define ACC4(v)                                                                  \
    do {                                                                         \
        aL0 += __uint_as_float((v).x << 16); aH0 += __uint_as_float((v).x & 0xFFFF0000u); \
        aL1 += __uint_as_float((v).y << 16); aH1 += __uint_as_float((v).y & 0xFFFF0000u); \
        aL2 += __uint_as_float((v).z << 16); aH2 += __uint_as_float((v).z & 0xFFFF0000u); \
        aL3 += __uint_as_float((v).w << 16); aH3 += __uint_as_float((v).w & 0xFFFF0000u); \
    } while (0)
    for (int base = 0; base < pd; base += 64) {
        int sidx = csr_src[e0 + base + lane];   // 64 slot indices (slack-guarded)
        int m = min(64, pd - base);             // multiple of 8
        int ns = m >> 3;                        // 1..8 wave-uniform
        uint4 v0, v1, v2, v3, v4, v5, v6, v7;
        { int s = __shfl(sidx, q);               v0 = rb[(size_t)s * 8 + d4]; }
        if (ns > 1) { int s = __shfl(sidx,  8 + q); v1 = rb[(size_t)s * 8 + d4]; }
        if (ns > 2) { int s = __shfl(sidx, 16 + q); v2 = rb[(size_t)s * 8 + d4]; }
        if (ns > 3) { int s = __shfl(sidx, 24 + q); v3 = rb[(size_t)s * 8 + d4]; }
        if (ns > 4) { int s = __shfl(sidx, 32 + q); v4 = rb[(size_t)s * 8 + d4]; }
        if (ns > 5) { int s = __shfl(sidx, 40 + q); v5 = rb[(size_t)s * 8 + d4]; }
        if (ns > 6) { int s = __shfl(sidx, 48 + q); v6 = rb[(size_t)s * 8 + d4]; }
        if (ns > 7) { int s = __shfl(sidx, 56 + q); v7 = rb[(size_t)s * 8 + d4]; }
        ACC4(v0);
        if (ns > 1) ACC4(v1);
        if (ns > 2) ACC4(v2);
        if (ns > 3) ACC4(v3);
        if (ns > 4) ACC4(v4);
        if (ns > 5) ACC4(v5);
        if (ns > 6) ACC4(v6);
        if (ns > 7) ACC4(v7);
    }
#undef ACC4
    // reduce partial sums over the 8 q-groups (lanes sharing d4)
#define RED8(a) { a += __shfl_xor(a, 8); a += __shfl_xor(a, 16); a += __shfl_xor(a, 32); }
    RED8(aL0) RED8(aH0) RED8(aL1) RED8(aH1)
    RED8(aL2) RED8(aH2) RED8(aL3) RED8(aH3)
#undef RED8
    uint4 sv = rb[(size_t)node * 8 + d4];    // self row (uniform node, L1-broadcast)
    float nr = norm[node];
    float w0 = wpan[0];
    float w01 = wpan[0] * wpan[1];
    float p0 = 0.f, p1 = 0.f, p2 = 0.f, p3 = 0.f;
#define PROJ(comp, aL, aH, i)                                                    \
    {                                                                            \
        float vL = fmaxf(nr * (w0 * __uint_as_float((comp) << 16) + w01 * aL), 0.0f); \
        float vH = fmaxf(nr * (w0 * __uint_as_float((comp) & 0xFFFF0000u) + w01 * aH), 0.0f); \
        float4 wl = *(const float4*)(w44 + (size_t)(8 * d4 + 2 * i) * 4);        \
        float4 wh = *(const float4*)(w44 + (size_t)(8 * d4 + 2 * i + 1) * 4);    \
        p0 += vL * wl.x + vH * wh.x; p1 += vL * wl.y + vH * wh.y;                \
        p2 += vL * wl.z + vH * wh.z; p3 += vL * wl.w + vH * wh.w;                \
    }
    PROJ(sv.x, aL0, aH0, 0)
    PROJ(sv.y, aL1, aH1, 1)
    PROJ(sv.z, aL2, aH2, 2)
    PROJ(sv.w, aL3, aH3, 3)
#undef PROJ
    // reduce projection over the 8 d4 slots (lanes 0..7 cover all 64 channels)
    for (int off = 4; off; off >>= 1) {
        p0 += __shfl_xor(p0, off);
        p1 += __shfl_xor(p1, off);
        p2 += __shfl_xor(p2, off);
        p3 += __shfl_xor(p3, off);
    }
    if (lane == 0) {
        float4 bb = *(const float4*)bias4;
        *(float4*)(u + node * 4) =
            make_float4(p0 + bb.x, p1 + bb.y, p2 + bb.z, p3 + bb.w);
    }
}

// Layer-2 aggregate on the rank-4 table (x8-padded rows, branch-free):
// pq[n,j] = norm*(w0*u[n,j] + w01*sum u[src,j]).
__global__ void agg_pq4_kernel(const float* __restrict__ u, const int* __restrict__ row_start,
                               const int* __restrict__ row_pdeg,
                               const int* __restrict__ csr_src,
                               const float* __restrict__ norm,
                               const float* __restrict__ wpan, float* __restrict__ pq,
                               int n_nodes) {
    int t = threadIdx.x;
    int node = blockIdx.x * 64 + (t >> 2);
    int j = t & 3;
    if (node >= n_nodes) return;
    int e0 = row_start[node];
    int pd = row_pdeg[node];
    float acc = 0.0f;
    for (int e = 0; e < pd; e += 8) {
#pragma unroll
        for (int k = 0; k < 8; k++) {
            int s = csr_src[e0 + e + k];
            acc += u[s * 4 + j];
        }
    }
    float w0 = wpan[0];
    float w01 = wpan[0] * wpan[1];
    pq[node * 4 + j] = norm[node] * (w0 * u[node * 4 + j] + w01 * acc);
}

__global__ void edge_out_kernel(const int* __restrict__ src, const int* __restrict__ dst,
                                const float* __restrict__ pq, const float* __restrict__ bc,
                                float* __restrict__ out, int n_edges) {
    int e = blockIdx.x * blockDim.x + threadIdx.x;
    if (e >= n_edges) return;
    int r = src[e], c = dst[e];
    float2 p = *(const float2*)(pq + r * 4);
    float2 q = *(const float2*)(pq + c * 4 + 2);
    float2 o = make_float2(p.x + q.x + bc[0], p.y + q.y + bc[1]);
    *(float2*)(out + e * 2) = o;
}

extern "C" void kernel_launch(void* const* d_in, const int* in_sizes, int n_in,
                              void* d_out, int out_size, void* d_ws, size_t ws_size,
                              hipStream_t stream) {
    const float* x      = (const float*)d_in[0];
    const int*   eidx   = (const int*)d_in[1];
    const float* w1_lin = (const float*)d_in[2];
    const float* b1_lin = (const float*)d_in[3];
    const float* w1_pan = (const float*)d_in[4];
    const float* w2_lin = (const float*)d_in[5];
    const float* b2_lin = (const float*)d_in[6];
    const float* w2_pan = (const float*)d_in[7];
    const float* wc     = (const float*)d_in[8];
    const float* bc     = (const float*)d_in[9];
    float* out = (float*)d_out;

    const int* src = eidx;           // edge_index[0]
    const int* dst = eidx + NEDGES;  // edge_index[1]

    // ---- workspace carve-up (all 256B-aligned) ----
    char* ws = (char*)d_ws;
    size_t off = 0;
    auto carve = [&](size_t bytes) {
        char* p = ws + off;
        off = (off + bytes + 255) & ~(size_t)255;
        return p;
    };
    int*   bucket_fill = (int*)carve((size_t)NB * 4);
    int*   row_start = (int*)carve((size_t)NNODES * 4);
    int*   row_pdeg  = (int*)carve((size_t)NNODES * 4);
    unsigned int* staging = (unsigned int*)carve((size_t)NB * CAP * 4);   // 12.8 MB
    int*   csr_src  = (int*)carve(((size_t)NB * CAPE + 256) * 4);         // 12.8 MB + slack
    float* nrm      = (float*)carve((size_t)NNODES * 4);
    unsigned short* bufA = (unsigned short*)carve((size_t)(NNODES + 1) * HIDC * 2);
    float* u        = (float*)carve((size_t)(NNODES + 1) * 4 * 4);
    float* pq       = (float*)carve((size_t)NNODES * 4 * 4);
    float* w44      = (float*)carve((size_t)64 * 4 * 4);
    float* bias4    = (float*)carve((size_t)4 * 4);
    unsigned short* wTh = (unsigned short*)carve((size_t)HIDC * INC * 2); // 16 KB
    unsigned short* wTl = (unsigned short*)carve((size_t)HIDC * INC * 2); // 16 KB
    (void)ws_size; (void)in_sizes; (void)n_in; (void)out_size;

    hipMemsetAsync(bucket_fill, 0, (size_t)NB * 4, stream);

    // prep: wT bf16 hi/lo split + w44/bias4 fold + bufA sentinel row
    prep_w_kernel<<<32, 256, 0, stream>>>(w1_lin, wTh, wTl, w2_lin, b2_lin, wc,
                                          w44, bias4, bufA);

    // fat kernel: edge binning (first 196 blocks) || layer-1 MFMA GEMM
    fat_kernel<<<NBLK_FILL + NBLK_LIN, 256, 0, stream>>>(
        x, wTh, wTl, b1_lin, bufA, src, dst, bucket_fill, staging);

    // CSR build pass 2: x8-padded rows + row_start/pdeg + dedup + norm + scatter
    fill2_kernel<<<NB, 256, 0, stream>>>(bucket_fill, staging, csr_src, row_start, row_pdeg,
                                         nrm, NNODES);

    // layer 1 aggregate+relu fused with rank-4 projection -> u (1 node/wave, x4 gathers)
    agg_h_kernel<<<(NNODES + 3) / 4, 256, 0, stream>>>(
        (const unsigned int*)bufA, row_start, row_pdeg, csr_src, nrm, w1_pan, w44, bias4,
        u, NNODES);

    // layer 2 aggregate on the rank-4 table
    agg_pq4_kernel<<<(NNODES + 63) / 64, 256, 0, stream>>>(
        u, row_start, row_pdeg, csr_src, nrm, w2_pan, pq, NNODES);

    // edge head: out[e] = p[src[e]] + q[dst[e]] + bc
    edge_out_kernel<<<NEDGES / 256, 256, 0, stream>>>(src, dst, pq, bc, out, NEDGES);
}

// Round 3
// 255.741 us; speedup vs baseline: 1.1999x; 1.1999x over previous
//
#include <hip/hip_runtime.h>
#include <hip/hip_bf16.h>

#define NNODES 100000
#define NEDGES 1600000
#define INC 128
#define HIDC 64
#define BSHIFT 8                      // 256 nodes per bucket
#define NB ((NNODES + 255) / 256)     // 391 buckets
#define TILE 8192                     // edges per fill1 workgroup (32/thread)
#define HSLOTS 8192                   // LDS hash slots in fill2 (32 KB)
#define CAP 8192                      // staging words per bucket (avg load ~4092)
#define CAPE 8192                     // csr words per bucket (rows padded to x8)
#define NBLK_FILL ((NEDGES + TILE - 1) / TILE)   // 196
#define NBLK_LIN ((NNODES + 63) / 64)            // 1563

typedef short bf16x8 __attribute__((ext_vector_type(8)));
typedef float f32x4 __attribute__((ext_vector_type(4)));

__device__ __forceinline__ float bf2f(unsigned short h) {
    return __uint_as_float((unsigned)h << 16);
}
__device__ __forceinline__ unsigned short f2bf(float f) {
    __hip_bfloat16 h = __float2bfloat16(f);
    return *(unsigned short*)&h;
}

// ---- prep kernel: w1 -> transposed bf16 hi/lo split; w44/bias4 fold; sentinel ----
__global__ __launch_bounds__(256) void prep_w_kernel(
        const float* __restrict__ w1, unsigned short* __restrict__ wTh,
        unsigned short* __restrict__ wTl,
        const float* __restrict__ w2_lin, const float* __restrict__ b2,
        const float* __restrict__ wc, float* __restrict__ w44,
        float* __restrict__ bias4, unsigned short* __restrict__ out) {
    int t = threadIdx.x;
    int e = blockIdx.x * 256 + t;            // 0..8191 over wT[64][128]
    int c = e >> 7, k = e & 127;
    float v = w1[k * 64 + c];
    unsigned short hi = f2bf(v);
    wTh[e] = hi;
    wTl[e] = f2bf(v - bf2f(hi));
    if (blockIdx.x == 0) {
        if (t < 16)   // zero sentinel row for padded gathers
            *(ushort4*)(out + (size_t)NNODES * 64 + t * 4) = make_ushort4(0, 0, 0, 0);
        int kk = t >> 2, j = t & 3;
        float a = 0.0f;
#pragma unroll 8
        for (int i = 0; i < 64; i++) {
            float w4 = (j < 2) ? wc[i * 2 + j] : wc[(64 + i) * 2 + (j - 2)];
            a += w2_lin[kk * 64 + i] * w4;
        }
        w44[kk * 4 + j] = a;
        if (kk == 0) {
            float bb4 = 0.0f;
            for (int i = 0; i < 64; i++) {
                float w4 = (j < 2) ? wc[i * 2 + j] : wc[(64 + i) * 2 + (j - 2)];
                bb4 += b2[i] * w4;
            }
            bias4[j] = bb4;
        }
    }
}

// ---- fat kernel: fill1 binning (blocks [0, NBLK_FILL)) + MFMA lin1 GEMM (rest) ----
// GEMM is bf16x3 error-compensated: x = xh+xl, w = wh+wl (bf16 each);
// h = xh*wh + xh*wl + xl*wh  (xl*wl term ~2^-18 rel, dropped).
__global__ __launch_bounds__(256) void fat_kernel(
        const float* __restrict__ x,
        const unsigned short* __restrict__ wTh, const unsigned short* __restrict__ wTl,
        const float* __restrict__ b, unsigned short* __restrict__ out,
        const int* __restrict__ src, const int* __restrict__ dst,
        int* __restrict__ bucket_fill, unsigned int* __restrict__ staging) {
    __shared__ alignas(16) unsigned short s_a[2][64 * 128];  // x hi/lo, 32 KB, swizzled
    __shared__ alignas(16) unsigned short s_b[2][64 * 128];  // wT hi/lo, 32 KB, swizzled
    int t = threadIdx.x;
    if (blockIdx.x < NBLK_FILL) {
        // ---------------- fill1 branch ----------------
        int* cnt = (int*)&s_a[0][0];
        int* basepos = cnt + NB;
        unsigned int* svl = (unsigned int*)&s_b[0][0];   // 8192 words = TILE
        for (int i = t; i < NB; i += 256) cnt[i] = 0;
        __syncthreads();
        int tile0 = blockIdx.x * TILE;
        int meta[32];
#pragma unroll
        for (int i = 0; i < 32; i++) {
            int e = tile0 + i * 256 + t;
            meta[i] = -1;
            if (e < NEDGES) {
                int s = src[e], d = dst[e];
                int bkt = d >> BSHIFT;
                int r = atomicAdd(&cnt[bkt], 1);     // < TILE = 8192 (13 bits)
                meta[i] = (bkt << 13) | r;
                svl[i * 256 + t] = ((unsigned)(d & 255) << 17) | (unsigned)s;
            }
        }
        __syncthreads();
        for (int i = t; i < NB; i += 256) {
            int c = cnt[i];
            int g = (c > 0) ? atomicAdd(&bucket_fill[i], c) : 0;
            basepos[i] = (i << 13) + g;              // staging region = [i*CAP, ...)
        }
        __syncthreads();
#pragma unroll
        for (int i = 0; i < 32; i++) {
            if (meta[i] >= 0) {
                int bkt = meta[i] >> 13, r = meta[i] & 8191;
                staging[basepos[bkt] + r] = svl[i * 256 + t];
            }
        }
    } else {
        // ---------------- MFMA GEMM branch: 64 nodes x 64 cols, K=128 ----------------
        int node0 = (blockIdx.x - NBLK_FILL) * 64;
        float4 vx[8];
#pragma unroll
        for (int it = 0; it < 8; it++) {
            int idx = it * 256 + t;                  // 0..2047 float4s of x tile
            int row = idx >> 5, c4 = idx & 31;
            int node = node0 + row;
            if (node < NNODES)
                vx[it] = *(const float4*)(x + (size_t)node * INC + c4 * 4);
            else
                vx[it] = make_float4(0.f, 0.f, 0.f, 0.f);
        }
        uint4 vwh[4], vwl[4];
#pragma unroll
        for (int j = 0; j < 4; j++) {
            vwh[j] = *(const uint4*)(wTh + (size_t)(j * 256 + t) * 8);
            vwl[j] = *(const uint4*)(wTl + (size_t)(j * 256 + t) * 8);
        }
        // convert x -> bf16 hi/lo, write LDS swizzled (k ^= (row&7)<<3, elem units)
#pragma unroll
        for (int it = 0; it < 8; it++) {
            int idx = it * 256 + t;
            int row = idx >> 5, c4 = idx & 31;
            ushort4 hi, lo;
            hi.x = f2bf(vx[it].x); lo.x = f2bf(vx[it].x - bf2f(hi.x));
            hi.y = f2bf(vx[it].y); lo.y = f2bf(vx[it].y - bf2f(hi.y));
            hi.z = f2bf(vx[it].z); lo.z = f2bf(vx[it].z - bf2f(hi.z));
            hi.w = f2bf(vx[it].w); lo.w = f2bf(vx[it].w - bf2f(hi.w));
            int ke = (c4 * 4) ^ ((row & 7) << 3);
            *(ushort4*)&s_a[0][row * 128 + ke] = hi;
            *(ushort4*)&s_a[1][row * 128 + ke] = lo;
        }
#pragma unroll
        for (int j = 0; j < 4; j++) {
            int idx = j * 256 + t;                   // ushort8 chunk of wT[64][128]
            int col = idx >> 4, k0 = (idx & 15) * 8;
            int ke = k0 ^ ((col & 7) << 3);
            *(uint4*)&s_b[0][col * 128 + ke] = vwh[j];
            *(uint4*)&s_b[1][col * 128 + ke] = vwl[j];
        }
        __syncthreads();
        int l = t & 63, wv = t >> 6;
        int mr = l & 15, g = l >> 4;
        int arow = wv * 16 + mr;                     // arow&7 == mr&7 (wv*16 % 8 == 0)
        f32x4 acc[4] = {{0.f, 0.f, 0.f, 0.f}, {0.f, 0.f, 0.f, 0.f},
                        {0.f, 0.f, 0.f, 0.f}, {0.f, 0.f, 0.f, 0.f}};
#pragma unroll
        for (int ks = 0; ks < 4; ks++) {
            int k0 = ks * 32 + g * 8;
            int ko = k0 ^ ((mr & 7) << 3);
            bf16x8 ah = *(const bf16x8*)&s_a[0][arow * 128 + ko];
            bf16x8 al = *(const bf16x8*)&s_a[1][arow * 128 + ko];
#pragma unroll
            for (int cb = 0; cb < 4; cb++) {
                int bo = (cb * 16 + mr) * 128 + ko;
                bf16x8 bh = *(const bf16x8*)&s_b[0][bo];
                bf16x8 bl = *(const bf16x8*)&s_b[1][bo];
                acc[cb] = __builtin_amdgcn_mfma_f32_16x16x32_bf16(ah, bh, acc[cb], 0, 0, 0);
                acc[cb] = __builtin_amdgcn_mfma_f32_16x16x32_bf16(ah, bl, acc[cb], 0, 0, 0);
                acc[cb] = __builtin_amdgcn_mfma_f32_16x16x32_bf16(al, bh, acc[cb], 0, 0, 0);
            }
        }
#pragma unroll
        for (int cb = 0; cb < 4; cb++) {
            int col = cb * 16 + mr;
            float bb = b[col];
#pragma unroll
            for (int r = 0; r < 4; r++) {
                int node = node0 + wv * 16 + g * 4 + r;
                if (node < NNODES)
                    out[(size_t)node * 64 + col] = f2bf(acc[cb][r] + bb);
            }
        }
    }
}

// fill pass 2: one WG per 256-node bucket, fixed csr region [b*CAPE, ...).
// Rows padded to x8 with sentinel n_nodes (points at the zero row).
__global__ __launch_bounds__(256) void fill2_kernel(
        const int* __restrict__ bucket_fill, const unsigned int* __restrict__ staging,
        int* __restrict__ csr_src, int* __restrict__ row_start,
        int* __restrict__ row_pdeg, float* __restrict__ norm, int n_nodes) {
    __shared__ int cnt[256];
    __shared__ int dcount[256];
    __shared__ int off[256];
    __shared__ int pscan[256];
    __shared__ unsigned short rank16[CAP];   // 16 KB
    __shared__ unsigned int ht[HSLOTS];      // 32 KB
    int t = threadIdx.x;
    int b = blockIdx.x;
    int node0 = b << BSHIFT;
    int nn = min(256, n_nodes - node0);
    cnt[t] = 0; dcount[t] = 0;
    {
        uint4* h4 = (uint4*)ht;
        uint4 ff = make_uint4(0xFFFFFFFFu, 0xFFFFFFFFu, 0xFFFFFFFFu, 0xFFFFFFFFu);
        for (int i = t; i < HSLOTS / 4; i += 256) h4[i] = ff;
    }
    __syncthreads();
    int start = b << 13;
    int total = bucket_fill[b];
    // phase A: count + rank + dedup
    for (int li = t; li < total; li += 256) {
        unsigned int w = staging[start + li];
        int s = (int)(w & 0x1FFFFu);
        int dl = (int)(w >> 17);
        int r = atomicAdd(&cnt[dl], 1);
        rank16[li] = (unsigned short)r;
        if (s != node0 + dl) {  // self-loops merge with the I-diagonal
            unsigned int slot = ((w * 2654435761u) >> 13) & (HSLOTS - 1);
            while (true) {
                unsigned int prev = atomicCAS(&ht[slot], 0xFFFFFFFFu, w);
                if (prev == 0xFFFFFFFFu) { atomicAdd(&dcount[dl], 1); break; }
                if (prev == w) break;
                slot = (slot + 1) & (HSLOTS - 1);
            }
        }
    }
    __syncthreads();
    // exclusive prefix of x8-padded counts -> csr offsets within [b*CAPE, ...)
    int cv = cnt[t];
    int pv = (cv + 7) & ~7;
    pscan[t] = pv;
    __syncthreads();
    for (int o = 1; o < 256; o <<= 1) {
        int xx = (t >= o) ? pscan[t - o] : 0;
        __syncthreads();
        pscan[t] += xx;
        __syncthreads();
    }
    off[t] = b * CAPE + pscan[t] - pv;
    __syncthreads();
    if (t < nn) {
        row_start[node0 + t] = off[t];
        row_pdeg[node0 + t] = pv;
        norm[node0 + t] = 1.0f / (1.0f + (float)dcount[t]);
    }
    // sentinel-pad the tail of each row
    for (int k = cv; k < pv; k++) csr_src[off[t] + k] = n_nodes;
    // phase B: scatter csr
    for (int li = t; li < total; li += 256) {
        unsigned int w = staging[start + li];
        int s = (int)(w & 0x1FFFFu);
        int dl = (int)(w >> 17);
        csr_src[off[dl] + (int)rank16[li]] = s;
    }
}

// One wave per node; per-lane-dword gathers (2 rows per wave-load -- many small
// requests, the R1-proven pattern) with DEEP ISSUE: all of a chunk's loads
// (up to 32) are issued before any accumulation, so ~pd/2 loads are in flight
// per wave instead of ~4. Index distribution via one ds_bpermute per edge-pair
// (off the VALU). Lanes 0-31 process even edges (channel dword sl), lanes
// 32-63 odd edges; halves combined with one shfl_xor(32). Fused PAN combine +
// relu + rank-4 projection -> u. h1 never hits global memory.
__global__ void agg_h_kernel(const unsigned int* __restrict__ lin32,
                             const int* __restrict__ row_start,
                             const int* __restrict__ row_pdeg,
                             const int* __restrict__ csr_src,
                             const float* __restrict__ norm,
                             const float* __restrict__ wpan, const float* __restrict__ w44,
                             const float* __restrict__ bias4, float* __restrict__ u,
                             int n_nodes) {
    int t = threadIdx.x;
    int node = blockIdx.x * 4 + (t >> 6);
    int lane = t & 63;
    int sl = lane & 31;      // channel dword within the row
    int h5 = lane >> 5;      // edge parity (even/odd half of the wave)
    if (blockIdx.x == 0 && t < 4) u[n_nodes * 4 + t] = 0.0f;  // zero row for agg_pq4 pads
    if (node >= n_nodes) return;
    int e0 = row_start[node];
    int pd = row_pdeg[node];                 // multiple of 8
    float aLo[4] = {0.f, 0.f, 0.f, 0.f};
    float aHi[4] = {0.f, 0.f, 0.f, 0.f};
    for (int base = 0; base < pd; base += 64) {
        int sidx = csr_src[e0 + base + lane];   // 64 slot indices (slack-guarded)
        int m = min(64, pd - base);             // multiple of 8
        int ns = m >> 3;                        // 1..8, wave-uniform
        unsigned int wd[8][4];
        // ---- issue phase: group g = edges 8g..8g+7 -> 4 dword wave-loads ----
#pragma unroll
        for (int g = 0; g < 8; g++) {
            if (g < ns) {
                int i0 = __shfl(sidx, 8 * g + 0 + h5);   // load j covers edges
                int i1 = __shfl(sidx, 8 * g + 2 + h5);   // (8g+2j, 8g+2j+1)
                int i2 = __shfl(sidx, 8 * g + 4 + h5);
                int i3 = __shfl(sidx, 8 * g + 6 + h5);
                wd[g][0] = lin32[(size_t)i0 * 32 + sl];
                wd[g][1] = lin32[(size_t)i1 * 32 + sl];
                wd[g][2] = lin32[(size_t)i2 * 32 + sl];
                wd[g][3] = lin32[(size_t)i3 * 32 + sl];
            }
        }
        // ---- accumulate phase ----
#pragma unroll
        for (int g = 0; g < 8; g++) {
            if (g < ns) {
                aLo[0] += __uint_as_float(wd[g][0] << 16);
                aHi[0] += __uint_as_float(wd[g][0] & 0xFFFF0000u);
                aLo[1] += __uint_as_float(wd[g][1] << 16);
                aHi[1] += __uint_as_float(wd[g][1] & 0xFFFF0000u);
                aLo[2] += __uint_as_float(wd[g][2] << 16);
                aHi[2] += __uint_as_float(wd[g][2] & 0xFFFF0000u);
                aLo[3] += __uint_as_float(wd[g][3] << 16);
                aHi[3] += __uint_as_float(wd[g][3] & 0xFFFF0000u);
            }
        }
    }
    float accLo = (aLo[0] + aLo[1]) + (aLo[2] + aLo[3]);
    float accHi = (aHi[0] + aHi[1]) + (aHi[2] + aHi[3]);
    accLo += __shfl_xor(accLo, 32);          // combine even/odd edge halves
    accHi += __shfl_xor(accHi, 32);
    unsigned int wself = lin32[(size_t)node * 32 + sl];
    float nr = norm[node];
    float w0 = wpan[0];
    float w01 = wpan[0] * wpan[1];
    float vLo = fmaxf(nr * (w0 * __uint_as_float(wself << 16) + w01 * accLo), 0.0f);
    float vHi = fmaxf(nr * (w0 * __uint_as_float(wself & 0xFFFF0000u) + w01 * accHi), 0.0f);
    int c0 = 2 * sl;
    float4 wv0 = *(const float4*)(w44 + c0 * 4);
    float4 wv1 = *(const float4*)(w44 + (c0 + 1) * 4);
    float p0 = vLo * wv0.x + vHi * wv1.x;
    float p1 = vLo * wv0.y + vHi * wv1.y;
    float p2 = vLo * wv0.z + vHi * wv1.z;
    float p3 = vLo * wv0.w + vHi * wv1.w;
    for (int off = 16; off; off >>= 1) {     // reduce over 32 lanes (halves identical)
        p0 += __shfl_xor(p0, off);
        p1 += __shfl_xor(p1, off);
        p2 += __shfl_xor(p2, off);
        p3 += __shfl_xor(p3, off);
    }
    if (lane == 0) {
        float4 bb = *(const float4*)bias4;
        *(float4*)(u + node * 4) =
            make_float4(p0 + bb.x, p1 + bb.y, p2 + bb.z, p3 + bb.w);
    }
}

// Layer-2 aggregate on the rank-4 table (x8-padded rows, branch-free):
// pq[n,j] = norm*(w0*u[n,j] + w01*sum u[src,j]).
__global__ void agg_pq4_kernel(const float* __restrict__ u, const int* __restrict__ row_start,
                               const int* __restrict__ row_pdeg,
                               const int* __restrict__ csr_src,
                               const float* __restrict__ norm,
                               const float* __restrict__ wpan, float* __restrict__ pq,
                               int n_nodes) {
    int t = threadIdx.x;
    int node = blockIdx.x * 64 + (t >> 2);
    int j = t & 3;
    if (node >= n_nodes) return;
    int e0 = row_start[node];
    int pd = row_pdeg[node];
    float acc = 0.0f;
    for (int e = 0; e < pd; e += 8) {
#pragma unroll
        for (int k = 0; k < 8; k++) {
            int s = csr_src[e0 + e + k];
            acc += u[s * 4 + j];
        }
    }
    float w0 = wpan[0];
    float w01 = wpan[0] * wpan[1];
    pq[node * 4 + j] = norm[node] * (w0 * u[node * 4 + j] + w01 * acc);
}

__global__ void edge_out_kernel(const int* __restrict__ src, const int* __restrict__ dst,
                                const float* __restrict__ pq, const float* __restrict__ bc,
                                float* __restrict__ out, int n_edges) {
    int e = blockIdx.x * blockDim.x + threadIdx.x;
    if (e >= n_edges) return;
    int r = src[e], c = dst[e];
    float2 p = *(const float2*)(pq + r * 4);
    float2 q = *(const float2*)(pq + c * 4 + 2);
    float2 o = make_float2(p.x + q.x + bc[0], p.y + q.y + bc[1]);
    *(float2*)(out + e * 2) = o;
}

extern "C" void kernel_launch(void* const* d_in, const int* in_sizes, int n_in,
                              void* d_out, int out_size, void* d_ws, size_t ws_size,
                              hipStream_t stream) {
    const float* x      = (const float*)d_in[0];
    const int*   eidx   = (const int*)d_in[1];
    const float* w1_lin = (const float*)d_in[2];
    const float* b1_lin = (const float*)d_in[3];
    const float* w1_pan = (const float*)d_in[4];
    const float* w2_lin = (const float*)d_in[5];
    const float* b2_lin = (const float*)d_in[6];
    const float* w2_pan = (const float*)d_in[7];
    const float* wc     = (const float*)d_in[8];
    const float* bc     = (const float*)d_in[9];
    float* out = (float*)d_out;

    const int* src = eidx;           // edge_index[0]
    const int* dst = eidx + NEDGES;  // edge_index[1]

    // ---- workspace carve-up (all 256B-aligned) ----
    char* ws = (char*)d_ws;
    size_t off = 0;
    auto carve = [&](size_t bytes) {
        char* p = ws + off;
        off = (off + bytes + 255) & ~(size_t)255;
        return p;
    };
    int*   bucket_fill = (int*)carve((size_t)NB * 4);
    int*   row_start = (int*)carve((size_t)NNODES * 4);
    int*   row_pdeg  = (int*)carve((size_t)NNODES * 4);
    unsigned int* staging = (unsigned int*)carve((size_t)NB * CAP * 4);   // 12.8 MB
    int*   csr_src  = (int*)carve(((size_t)NB * CAPE + 256) * 4);         // 12.8 MB + slack
    float* nrm      = (float*)carve((size_t)NNODES * 4);
    unsigned short* bufA = (unsigned short*)carve((size_t)(NNODES + 1) * HIDC * 2);
    float* u        = (float*)carve((size_t)(NNODES + 1) * 4 * 4);
    float* pq       = (float*)carve((size_t)NNODES * 4 * 4);
    float* w44      = (float*)carve((size_t)64 * 4 * 4);
    float* bias4    = (float*)carve((size_t)4 * 4);
    unsigned short* wTh = (unsigned short*)carve((size_t)HIDC * INC * 2); // 16 KB
    unsigned short* wTl = (unsigned short*)carve((size_t)HIDC * INC * 2); // 16 KB
    (void)ws_size; (void)in_sizes; (void)n_in; (void)out_size;

    hipMemsetAsync(bucket_fill, 0, (size_t)NB * 4, stream);

    // prep: wT bf16 hi/lo split + w44/bias4 fold + bufA sentinel row
    prep_w_kernel<<<32, 256, 0, stream>>>(w1_lin, wTh, wTl, w2_lin, b2_lin, wc,
                                          w44, bias4, bufA);

    // fat kernel: edge binning (first 196 blocks) || layer-1 MFMA GEMM
    fat_kernel<<<NBLK_FILL + NBLK_LIN, 256, 0, stream>>>(
        x, wTh, wTl, b1_lin, bufA, src, dst, bucket_fill, staging);

    // CSR build pass 2: x8-padded rows + row_start/pdeg + dedup + norm + scatter
    fill2_kernel<<<NB, 256, 0, stream>>>(bucket_fill, staging, csr_src, row_start, row_pdeg,
                                         nrm, NNODES);

    // layer 1 aggregate+relu fused with rank-4 projection -> u (1 node/wave, deep issue)
    agg_h_kernel<<<(NNODES + 3) / 4, 256, 0, stream>>>(
        (const unsigned int*)bufA, row_start, row_pdeg, csr_src, nrm, w1_pan, w44, bias4,
        u, NNODES);

    // layer 2 aggregate on the rank-4 table
    agg_pq4_kernel<<<(NNODES + 63) / 64, 256, 0, stream>>>(
        u, row_start, row_pdeg, csr_src, nrm, w2_pan, pq, NNODES);

    // edge head: out[e] = p[src[e]] + q[dst[e]] + bc
    edge_out_kernel<<<NEDGES / 256, 256, 0, stream>>>(src, dst, pq, bc, out, NEDGES);
}

// Round 4
// 244.009 us; speedup vs baseline: 1.2576x; 1.0481x over previous
//
#include <hip/hip_runtime.h>
#include <hip/hip_bf16.h>

#define NNODES 100000
#define NEDGES 1600000
#define INC 128
#define HIDC 64
#define BSHIFT 8                      // 256 nodes per bucket
#define NB ((NNODES + 255) / 256)     // 391 buckets
#define TILE 8192                     // edges per fill1 workgroup (32/thread)
#define HSLOTS 8192                   // LDS hash slots in fill2 (32 KB)
#define CAP 8192                      // staging words per bucket (avg load ~4092)
#define CAPE 8192                     // csr words per bucket (rows padded to x8)
#define NBLK_FILL ((NEDGES + TILE - 1) / TILE)   // 196
#define NBLK_LIN ((NNODES + 63) / 64)            // 1563

typedef short bf16x8 __attribute__((ext_vector_type(8)));
typedef float f32x4 __attribute__((ext_vector_type(4)));

__device__ __forceinline__ float bf2f(unsigned short h) {
    return __uint_as_float((unsigned)h << 16);
}
__device__ __forceinline__ unsigned short f2bf(float f) {
    __hip_bfloat16 h = __float2bfloat16(f);
    return *(unsigned short*)&h;
}

// ---- prep kernel: w1 -> transposed bf16 hi/lo split; w44/bias4 fold; sentinel ----
__global__ __launch_bounds__(256) void prep_w_kernel(
        const float* __restrict__ w1, unsigned short* __restrict__ wTh,
        unsigned short* __restrict__ wTl,
        const float* __restrict__ w2_lin, const float* __restrict__ b2,
        const float* __restrict__ wc, float* __restrict__ w44,
        float* __restrict__ bias4, unsigned short* __restrict__ out) {
    int t = threadIdx.x;
    int e = blockIdx.x * 256 + t;            // 0..8191 over wT[64][128]
    int c = e >> 7, k = e & 127;
    float v = w1[k * 64 + c];
    unsigned short hi = f2bf(v);
    wTh[e] = hi;
    wTl[e] = f2bf(v - bf2f(hi));
    if (blockIdx.x == 0) {
        if (t < 16)   // zero sentinel row for padded gathers
            *(ushort4*)(out + (size_t)NNODES * 64 + t * 4) = make_ushort4(0, 0, 0, 0);
        int kk = t >> 2, j = t & 3;
        float a = 0.0f;
#pragma unroll 8
        for (int i = 0; i < 64; i++) {
            float w4 = (j < 2) ? wc[i * 2 + j] : wc[(64 + i) * 2 + (j - 2)];
            a += w2_lin[kk * 64 + i] * w4;
        }
        w44[kk * 4 + j] = a;
        if (kk == 0) {
            float bb4 = 0.0f;
            for (int i = 0; i < 64; i++) {
                float w4 = (j < 2) ? wc[i * 2 + j] : wc[(64 + i) * 2 + (j - 2)];
                bb4 += b2[i] * w4;
            }
            bias4[j] = bb4;
        }
    }
}

// ---- fat kernel: fill1 binning (blocks [0, NBLK_FILL)) + MFMA lin1 GEMM (rest) ----
// GEMM is bf16x3 error-compensated: x = xh+xl, w = wh+wl (bf16 each);
// h = xh*wh + xh*wl + xl*wh  (xl*wl term ~2^-18 rel, dropped).
__global__ __launch_bounds__(256) void fat_kernel(
        const float* __restrict__ x,
        const unsigned short* __restrict__ wTh, const unsigned short* __restrict__ wTl,
        const float* __restrict__ b, unsigned short* __restrict__ out,
        const int* __restrict__ src, const int* __restrict__ dst,
        int* __restrict__ bucket_fill, unsigned int* __restrict__ staging) {
    __shared__ alignas(16) unsigned short s_a[2][64 * 128];  // x hi/lo, 32 KB, swizzled
    __shared__ alignas(16) unsigned short s_b[2][64 * 128];  // wT hi/lo, 32 KB, swizzled
    int t = threadIdx.x;
    if (blockIdx.x < NBLK_FILL) {
        // ---------------- fill1 branch ----------------
        int* cnt = (int*)&s_a[0][0];
        int* basepos = cnt + NB;
        unsigned int* svl = (unsigned int*)&s_b[0][0];   // 8192 words = TILE
        for (int i = t; i < NB; i += 256) cnt[i] = 0;
        __syncthreads();
        int tile0 = blockIdx.x * TILE;
        int meta[32];
#pragma unroll
        for (int i = 0; i < 32; i++) {
            int e = tile0 + i * 256 + t;
            meta[i] = -1;
            if (e < NEDGES) {
                int s = src[e], d = dst[e];
                int bkt = d >> BSHIFT;
                int r = atomicAdd(&cnt[bkt], 1);     // < TILE = 8192 (13 bits)
                meta[i] = (bkt << 13) | r;
                svl[i * 256 + t] = ((unsigned)(d & 255) << 17) | (unsigned)s;
            }
        }
        __syncthreads();
        for (int i = t; i < NB; i += 256) {
            int c = cnt[i];
            int g = (c > 0) ? atomicAdd(&bucket_fill[i], c) : 0;
            basepos[i] = (i << 13) + g;              // staging region = [i*CAP, ...)
        }
        __syncthreads();
#pragma unroll
        for (int i = 0; i < 32; i++) {
            if (meta[i] >= 0) {
                int bkt = meta[i] >> 13, r = meta[i] & 8191;
                staging[basepos[bkt] + r] = svl[i * 256 + t];
            }
        }
    } else {
        // ---------------- MFMA GEMM branch: 64 nodes x 64 cols, K=128 ----------------
        int node0 = (blockIdx.x - NBLK_FILL) * 64;
        float4 vx[8];
#pragma unroll
        for (int it = 0; it < 8; it++) {
            int idx = it * 256 + t;                  // 0..2047 float4s of x tile
            int row = idx >> 5, c4 = idx & 31;
            int node = node0 + row;
            if (node < NNODES)
                vx[it] = *(const float4*)(x + (size_t)node * INC + c4 * 4);
            else
                vx[it] = make_float4(0.f, 0.f, 0.f, 0.f);
        }
        uint4 vwh[4], vwl[4];
#pragma unroll
        for (int j = 0; j < 4; j++) {
            vwh[j] = *(const uint4*)(wTh + (size_t)(j * 256 + t) * 8);
            vwl[j] = *(const uint4*)(wTl + (size_t)(j * 256 + t) * 8);
        }
        // convert x -> bf16 hi/lo, write LDS swizzled (k ^= (row&7)<<3, elem units)
#pragma unroll
        for (int it = 0; it < 8; it++) {
            int idx = it * 256 + t;
            int row = idx >> 5, c4 = idx & 31;
            ushort4 hi, lo;
            hi.x = f2bf(vx[it].x); lo.x = f2bf(vx[it].x - bf2f(hi.x));
            hi.y = f2bf(vx[it].y); lo.y = f2bf(vx[it].y - bf2f(hi.y));
            hi.z = f2bf(vx[it].z); lo.z = f2bf(vx[it].z - bf2f(hi.z));
            hi.w = f2bf(vx[it].w); lo.w = f2bf(vx[it].w - bf2f(hi.w));
            int ke = (c4 * 4) ^ ((row & 7) << 3);
            *(ushort4*)&s_a[0][row * 128 + ke] = hi;
            *(ushort4*)&s_a[1][row * 128 + ke] = lo;
        }
#pragma unroll
        for (int j = 0; j < 4; j++) {
            int idx = j * 256 + t;                   // ushort8 chunk of wT[64][128]
            int col = idx >> 4, k0 = (idx & 15) * 8;
            int ke = k0 ^ ((col & 7) << 3);
            *(uint4*)&s_b[0][col * 128 + ke] = vwh[j];
            *(uint4*)&s_b[1][col * 128 + ke] = vwl[j];
        }
        __syncthreads();
        int l = t & 63, wv = t >> 6;
        int mr = l & 15, g = l >> 4;
        int arow = wv * 16 + mr;                     // arow&7 == mr&7 (wv*16 % 8 == 0)
        f32x4 acc[4] = {{0.f, 0.f, 0.f, 0.f}, {0.f, 0.f, 0.f, 0.f},
                        {0.f, 0.f, 0.f, 0.f}, {0.f, 0.f, 0.f, 0.f}};
#pragma unroll
        for (int ks = 0; ks < 4; ks++) {
            int k0 = ks * 32 + g * 8;
            int ko = k0 ^ ((mr & 7) << 3);
            bf16x8 ah = *(const bf16x8*)&s_a[0][arow * 128 + ko];
            bf16x8 al = *(const bf16x8*)&s_a[1][arow * 128 + ko];
#pragma unroll
            for (int cb = 0; cb < 4; cb++) {
                int bo = (cb * 16 + mr) * 128 + ko;
                bf16x8 bh = *(const bf16x8*)&s_b[0][bo];
                bf16x8 bl = *(const bf16x8*)&s_b[1][bo];
                acc[cb] = __builtin_amdgcn_mfma_f32_16x16x32_bf16(ah, bh, acc[cb], 0, 0, 0);
                acc[cb] = __builtin_amdgcn_mfma_f32_16x16x32_bf16(ah, bl, acc[cb], 0, 0, 0);
                acc[cb] = __builtin_amdgcn_mfma_f32_16x16x32_bf16(al, bh, acc[cb], 0, 0, 0);
            }
        }
#pragma unroll
        for (int cb = 0; cb < 4; cb++) {
            int col = cb * 16 + mr;
            float bb = b[col];
#pragma unroll
            for (int r = 0; r < 4; r++) {
                int node = node0 + wv * 16 + g * 4 + r;
                if (node < NNODES)
                    out[(size_t)node * 64 + col] = f2bf(acc[cb][r] + bb);
            }
        }
    }
}

// fill pass 2: one WG per 256-node bucket, fixed csr region [b*CAPE, ...).
// Rows padded to x8 with sentinel n_nodes (points at the zero row).
// csr_src now stores BYTE offsets (s*128) of the 128-B bufA rows.
__global__ __launch_bounds__(256) void fill2_kernel(
        const int* __restrict__ bucket_fill, const unsigned int* __restrict__ staging,
        int* __restrict__ csr_src, int* __restrict__ row_start,
        int* __restrict__ row_pdeg, float* __restrict__ norm, int n_nodes) {
    __shared__ int cnt[256];
    __shared__ int dcount[256];
    __shared__ int off[256];
    __shared__ int pscan[256];
    __shared__ unsigned short rank16[CAP];   // 16 KB
    __shared__ unsigned int ht[HSLOTS];      // 32 KB
    int t = threadIdx.x;
    int b = blockIdx.x;
    int node0 = b << BSHIFT;
    int nn = min(256, n_nodes - node0);
    cnt[t] = 0; dcount[t] = 0;
    {
        uint4* h4 = (uint4*)ht;
        uint4 ff = make_uint4(0xFFFFFFFFu, 0xFFFFFFFFu, 0xFFFFFFFFu, 0xFFFFFFFFu);
        for (int i = t; i < HSLOTS / 4; i += 256) h4[i] = ff;
    }
    __syncthreads();
    int start = b << 13;
    int total = bucket_fill[b];
    // phase A: count + rank + dedup
    for (int li = t; li < total; li += 256) {
        unsigned int w = staging[start + li];
        int s = (int)(w & 0x1FFFFu);
        int dl = (int)(w >> 17);
        int r = atomicAdd(&cnt[dl], 1);
        rank16[li] = (unsigned short)r;
        if (s != node0 + dl) {  // self-loops merge with the I-diagonal
            unsigned int slot = ((w * 2654435761u) >> 13) & (HSLOTS - 1);
            while (true) {
                unsigned int prev = atomicCAS(&ht[slot], 0xFFFFFFFFu, w);
                if (prev == 0xFFFFFFFFu) { atomicAdd(&dcount[dl], 1); break; }
                if (prev == w) break;
                slot = (slot + 1) & (HSLOTS - 1);
            }
        }
    }
    __syncthreads();
    // exclusive prefix of x8-padded counts -> csr offsets within [b*CAPE, ...)
    int cv = cnt[t];
    int pv = (cv + 7) & ~7;
    pscan[t] = pv;
    __syncthreads();
    for (int o = 1; o < 256; o <<= 1) {
        int xx = (t >= o) ? pscan[t - o] : 0;
        __syncthreads();
        pscan[t] += xx;
        __syncthreads();
    }
    off[t] = b * CAPE + pscan[t] - pv;
    __syncthreads();
    if (t < nn) {
        row_start[node0 + t] = off[t];
        row_pdeg[node0 + t] = pv;
        norm[node0 + t] = 1.0f / (1.0f + (float)dcount[t]);
    }
    // sentinel-pad the tail of each row (byte offset of the zero row)
    for (int k = cv; k < pv; k++) csr_src[off[t] + k] = n_nodes << 7;
    // phase B: scatter csr (byte offsets: s*128)
    for (int li = t; li < total; li += 256) {
        unsigned int w = staging[start + li];
        int s = (int)(w & 0x1FFFFu);
        int dl = (int)(w >> 17);
        csr_src[off[dl] + (int)rank16[li]] = s << 7;
    }
}

// Two nodes per wave: lanes 0-31 own node A (=2*pair), lanes 32-63 node B.
// Each dword wave-load fetches 2 full 128-B h1 rows (one edge of A + one of B)
// -- the proven R1 memory pattern -- while wave count and per-node fixed cost
// halve. Indices distributed via readlane (SGPR, no lgkm dep) + one cndmask.
// csr holds pre-shifted byte offsets so gather addressing is a single v_add.
// Tail slots clamp to the sentinel zero row. Fused PAN combine + relu +
// rank-4 projection -> u; h1 never hits global memory.
__global__ void agg_h_kernel(const unsigned int* __restrict__ lin32,
                             const int* __restrict__ row_start,
                             const int* __restrict__ row_pdeg,
                             const int* __restrict__ csr_src,
                             const float* __restrict__ norm,
                             const float* __restrict__ wpan, const float* __restrict__ w44,
                             const float* __restrict__ bias4, float* __restrict__ u,
                             int n_nodes) {
    int t = threadIdx.x;
    int lane = t & 63;
    int sl = lane & 31;                      // channel dword / edge slot
    int h5 = lane >> 5;                      // 0: node A, 1: node B
    int pair = blockIdx.x * 4 + (t >> 6);
    int node = pair * 2 + h5;                // own node for this half
    if (blockIdx.x == 0 && t < 4) u[n_nodes * 4 + t] = 0.0f;  // zero row for agg_pq4 pads
    if (pair * 2 >= n_nodes) return;
    bool valid = (node < n_nodes);
    int nc = valid ? node : 0;
    int e0 = row_start[nc];
    int pd = valid ? row_pdeg[nc] : 0;       // multiple of 8
    int pmax = max(pd, __shfl_xor(pd, 32));  // wave-uniform chunk bound
    int sentB = n_nodes << 7;                // byte offset of the zero row
    unsigned sl4 = (unsigned)sl * 4;
    const char* base8 = (const char*)lin32;
    float aLo0 = 0.f, aHi0 = 0.f, aLo1 = 0.f, aHi1 = 0.f;
    for (int base = 0; base < pmax; base += 32) {
        int li = base + sl;                  // own-row edge slot for this lane
        int so = (li < pd) ? csr_src[e0 + li] : sentB;   // byte offset (or sentinel)
        int m = min(32, pmax - base);        // wave-uniform
#pragma unroll
        for (int i = 0; i < 32; i += 2) {
            if (i < m) {
                int sA0 = __builtin_amdgcn_readlane(so, i);
                int sB0 = __builtin_amdgcn_readlane(so, 32 + i);
                int sA1 = __builtin_amdgcn_readlane(so, i + 1);
                int sB1 = __builtin_amdgcn_readlane(so, 33 + i);
                int so0 = h5 ? sB0 : sA0;
                int so1 = h5 ? sB1 : sA1;
                unsigned int wd0 = *(const unsigned int*)(base8 + (unsigned)(so0 + sl4));
                unsigned int wd1 = *(const unsigned int*)(base8 + (unsigned)(so1 + sl4));
                aLo0 += __uint_as_float(wd0 << 16);
                aHi0 += __uint_as_float(wd0 & 0xFFFF0000u);
                aLo1 += __uint_as_float(wd1 << 16);
                aHi1 += __uint_as_float(wd1 & 0xFFFF0000u);
            }
        }
    }
    float accLo = aLo0 + aLo1;
    float accHi = aHi0 + aHi1;
    // self row: per-lane own node's channel dword
    unsigned int wself = *(const unsigned int*)(base8 + (unsigned)((nc << 7) + sl4));
    float nr = norm[nc];
    float w0 = wpan[0];
    float w01 = wpan[0] * wpan[1];
    float vLo = fmaxf(nr * (w0 * __uint_as_float(wself << 16) + w01 * accLo), 0.0f);
    float vHi = fmaxf(nr * (w0 * __uint_as_float(wself & 0xFFFF0000u) + w01 * accHi), 0.0f);
    int c0 = 2 * sl;
    float4 wv0 = *(const float4*)(w44 + c0 * 4);
    float4 wv1 = *(const float4*)(w44 + (c0 + 1) * 4);
    float p0 = vLo * wv0.x + vHi * wv1.x;
    float p1 = vLo * wv0.y + vHi * wv1.y;
    float p2 = vLo * wv0.z + vHi * wv1.z;
    float p3 = vLo * wv0.w + vHi * wv1.w;
    for (int off = 16; off; off >>= 1) {     // reduce within the 32-lane half
        p0 += __shfl_xor(p0, off);
        p1 += __shfl_xor(p1, off);
        p2 += __shfl_xor(p2, off);
        p3 += __shfl_xor(p3, off);
    }
    if (sl == 0 && valid) {                  // lanes 0 and 32 write their nodes
        float4 bb = *(const float4*)bias4;
        *(float4*)(u + node * 4) =
            make_float4(p0 + bb.x, p1 + bb.y, p2 + bb.z, p3 + bb.w);
    }
}

// Layer-2 aggregate on the rank-4 table (x8-padded rows, branch-free):
// pq[n,j] = norm*(w0*u[n,j] + w01*sum u[src,j]).  csr holds s*128 byte offsets;
// u row start (float index) = s*4 = offset>>5.
__global__ void agg_pq4_kernel(const float* __restrict__ u, const int* __restrict__ row_start,
                               const int* __restrict__ row_pdeg,
                               const int* __restrict__ csr_src,
                               const float* __restrict__ norm,
                               const float* __restrict__ wpan, float* __restrict__ pq,
                               int n_nodes) {
    int t = threadIdx.x;
    int node = blockIdx.x * 64 + (t >> 2);
    int j = t & 3;
    if (node >= n_nodes) return;
    int e0 = row_start[node];
    int pd = row_pdeg[node];
    float acc = 0.0f;
    for (int e = 0; e < pd; e += 8) {
#pragma unroll
        for (int k = 0; k < 8; k++) {
            int so = csr_src[e0 + e + k];
            acc += u[(so >> 5) + j];
        }
    }
    float w0 = wpan[0];
    float w01 = wpan[0] * wpan[1];
    pq[node * 4 + j] = norm[node] * (w0 * u[node * 4 + j] + w01 * acc);
}

__global__ void edge_out_kernel(const int* __restrict__ src, const int* __restrict__ dst,
                                const float* __restrict__ pq, const float* __restrict__ bc,
                                float* __restrict__ out, int n_edges) {
    int e = blockIdx.x * blockDim.x + threadIdx.x;
    if (e >= n_edges) return;
    int r = src[e], c = dst[e];
    float2 p = *(const float2*)(pq + r * 4);
    float2 q = *(const float2*)(pq + c * 4 + 2);
    float2 o = make_float2(p.x + q.x + bc[0], p.y + q.y + bc[1]);
    *(float2*)(out + e * 2) = o;
}

extern "C" void kernel_launch(void* const* d_in, const int* in_sizes, int n_in,
                              void* d_out, int out_size, void* d_ws, size_t ws_size,
                              hipStream_t stream) {
    const float* x      = (const float*)d_in[0];
    const int*   eidx   = (const int*)d_in[1];
    const float* w1_lin = (const float*)d_in[2];
    const float* b1_lin = (const float*)d_in[3];
    const float* w1_pan = (const float*)d_in[4];
    const float* w2_lin = (const float*)d_in[5];
    const float* b2_lin = (const float*)d_in[6];
    const float* w2_pan = (const float*)d_in[7];
    const float* wc     = (const float*)d_in[8];
    const float* bc     = (const float*)d_in[9];
    float* out = (float*)d_out;

    const int* src = eidx;           // edge_index[0]
    const int* dst = eidx + NEDGES;  // edge_index[1]

    // ---- workspace carve-up (all 256B-aligned) ----
    char* ws = (char*)d_ws;
    size_t off = 0;
    auto carve = [&](size_t bytes) {
        char* p = ws + off;
        off = (off + bytes + 255) & ~(size_t)255;
        return p;
    };
    int*   bucket_fill = (int*)carve((size_t)NB * 4);
    int*   row_start = (int*)carve((size_t)NNODES * 4);
    int*   row_pdeg  = (int*)carve((size_t)NNODES * 4);
    unsigned int* staging = (unsigned int*)carve((size_t)NB * CAP * 4);   // 12.8 MB
    int*   csr_src  = (int*)carve(((size_t)NB * CAPE + 256) * 4);         // 12.8 MB + slack
    float* nrm      = (float*)carve((size_t)NNODES * 4);
    unsigned short* bufA = (unsigned short*)carve((size_t)(NNODES + 1) * HIDC * 2);
    float* u        = (float*)carve((size_t)(NNODES + 1) * 4 * 4);
    float* pq       = (float*)carve((size_t)NNODES * 4 * 4);
    float* w44      = (float*)carve((size_t)64 * 4 * 4);
    float* bias4    = (float*)carve((size_t)4 * 4);
    unsigned short* wTh = (unsigned short*)carve((size_t)HIDC * INC * 2); // 16 KB
    unsigned short* wTl = (unsigned short*)carve((size_t)HIDC * INC * 2); // 16 KB
    (void)ws_size; (void)in_sizes; (void)n_in; (void)out_size;

    hipMemsetAsync(bucket_fill, 0, (size_t)NB * 4, stream);

    // prep: wT bf16 hi/lo split + w44/bias4 fold + bufA sentinel row
    prep_w_kernel<<<32, 256, 0, stream>>>(w1_lin, wTh, wTl, w2_lin, b2_lin, wc,
                                          w44, bias4, bufA);

    // fat kernel: edge binning (first 196 blocks) || layer-1 MFMA GEMM
    fat_kernel<<<NBLK_FILL + NBLK_LIN, 256, 0, stream>>>(
        x, wTh, wTl, b1_lin, bufA, src, dst, bucket_fill, staging);

    // CSR build pass 2: x8-padded rows + row_start/pdeg + dedup + norm + scatter
    fill2_kernel<<<NB, 256, 0, stream>>>(bucket_fill, staging, csr_src, row_start, row_pdeg,
                                         nrm, NNODES);

    // layer 1 aggregate+relu fused with rank-4 projection -> u (2 nodes/wave)
    agg_h_kernel<<<(NNODES + 7) / 8, 256, 0, stream>>>(
        (const unsigned int*)bufA, row_start, row_pdeg, csr_src, nrm, w1_pan, w44, bias4,
        u, NNODES);

    // layer 2 aggregate on the rank-4 table
    agg_pq4_kernel<<<(NNODES + 63) / 64, 256, 0, stream>>>(
        u, row_start, row_pdeg, csr_src, nrm, w2_pan, pq, NNODES);

    // edge head: out[e] = p[src[e]] + q[dst[e]] + bc
    edge_out_kernel<<<NEDGES / 256, 256, 0, stream>>>(src, dst, pq, bc, out, NEDGES);
}

// Round 5
// 232.961 us; speedup vs baseline: 1.3172x; 1.0474x over previous
//
#include <hip/hip_runtime.h>
#include <hip/hip_bf16.h>

#define NNODES 100000
#define NEDGES 1600000
#define INC 128
#define HIDC 64
#define BSHIFT 7                      // 128 nodes per bucket
#define NB ((NNODES + 127) / 128)     // 782 buckets
#define TILE 4096                     // edges per fill1 workgroup (16/thread)
#define HSLOTS 4096                   // LDS hash slots in fill2 (16 KB)
#define CAP 4096                      // staging words per bucket (avg load ~2046)
#define CAPE 4096                     // csr words per bucket (rows padded to x8)
#define NBLK_FILL ((NEDGES + TILE - 1) / TILE)   // 391
#define NBLK_LIN ((NNODES + 63) / 64)            // 1563

typedef short bf16x8 __attribute__((ext_vector_type(8)));
typedef float f32x4 __attribute__((ext_vector_type(4)));

__device__ __forceinline__ float bf2f(unsigned short h) {
    return __uint_as_float((unsigned)h << 16);
}
__device__ __forceinline__ unsigned short f2bf(float f) {
    __hip_bfloat16 h = __float2bfloat16(f);
    return *(unsigned short*)&h;
}

// ---- prep kernel: w1 -> transposed bf16 hi/lo split; w44/bias4 fold; sentinel ----
__global__ __launch_bounds__(256) void prep_w_kernel(
        const float* __restrict__ w1, unsigned short* __restrict__ wTh,
        unsigned short* __restrict__ wTl,
        const float* __restrict__ w2_lin, const float* __restrict__ b2,
        const float* __restrict__ wc, float* __restrict__ w44,
        float* __restrict__ bias4, unsigned short* __restrict__ out) {
    int t = threadIdx.x;
    int e = blockIdx.x * 256 + t;            // 0..8191 over wT[64][128]
    int c = e >> 7, k = e & 127;
    float v = w1[k * 64 + c];
    unsigned short hi = f2bf(v);
    wTh[e] = hi;
    wTl[e] = f2bf(v - bf2f(hi));
    if (blockIdx.x == 0) {
        if (t < 16)   // zero sentinel row for padded gathers
            *(ushort4*)(out + (size_t)NNODES * 64 + t * 4) = make_ushort4(0, 0, 0, 0);
        int kk = t >> 2, j = t & 3;
        float a = 0.0f;
#pragma unroll 8
        for (int i = 0; i < 64; i++) {
            float w4 = (j < 2) ? wc[i * 2 + j] : wc[(64 + i) * 2 + (j - 2)];
            a += w2_lin[kk * 64 + i] * w4;
        }
        w44[kk * 4 + j] = a;
        if (kk == 0) {
            float bb4 = 0.0f;
            for (int i = 0; i < 64; i++) {
                float w4 = (j < 2) ? wc[i * 2 + j] : wc[(64 + i) * 2 + (j - 2)];
                bb4 += b2[i] * w4;
            }
            bias4[j] = bb4;
        }
    }
}

// ---- fat kernel: fill1 binning (blocks [0, NBLK_FILL)) + MFMA lin1 GEMM (rest) ----
// GEMM is bf16x3 error-compensated: x = xh+xl, w = wh+wl (bf16 each);
// h = xh*wh + xh*wl + xl*wh  (xl*wl term ~2^-18 rel, dropped).
__global__ __launch_bounds__(256) void fat_kernel(
        const float* __restrict__ x,
        const unsigned short* __restrict__ wTh, const unsigned short* __restrict__ wTl,
        const float* __restrict__ b, unsigned short* __restrict__ out,
        const int* __restrict__ src, const int* __restrict__ dst,
        int* __restrict__ bucket_fill, unsigned int* __restrict__ staging) {
    __shared__ alignas(16) unsigned short s_a[2][64 * 128];  // x hi/lo, 32 KB, swizzled
    __shared__ alignas(16) unsigned short s_b[2][64 * 128];  // wT hi/lo, 32 KB, swizzled
    int t = threadIdx.x;
    if (blockIdx.x < NBLK_FILL) {
        // ---------------- fill1 branch ----------------
        int* cnt = (int*)&s_a[0][0];
        int* basepos = cnt + NB;
        unsigned int* svl = (unsigned int*)&s_b[0][0];   // 4096 words = TILE
        for (int i = t; i < NB; i += 256) cnt[i] = 0;
        __syncthreads();
        int tile0 = blockIdx.x * TILE;
        int meta[16];
#pragma unroll
        for (int i = 0; i < 16; i++) {
            int e = tile0 + i * 256 + t;
            meta[i] = -1;
            if (e < NEDGES) {
                int s = src[e], d = dst[e];
                int bkt = d >> BSHIFT;
                int r = atomicAdd(&cnt[bkt], 1);     // < TILE = 4096 (12 bits)
                meta[i] = (bkt << 12) | r;
                svl[i * 256 + t] = ((unsigned)(d & 127) << 17) | (unsigned)s;
            }
        }
        __syncthreads();
        for (int i = t; i < NB; i += 256) {
            int c = cnt[i];
            int g = (c > 0) ? atomicAdd(&bucket_fill[i], c) : 0;
            basepos[i] = (i << 12) + g;              // staging region = [i*CAP, ...)
        }
        __syncthreads();
#pragma unroll
        for (int i = 0; i < 16; i++) {
            if (meta[i] >= 0) {
                int bkt = meta[i] >> 12, r = meta[i] & 4095;
                staging[basepos[bkt] + r] = svl[i * 256 + t];
            }
        }
    } else {
        // ---------------- MFMA GEMM branch: 64 nodes x 64 cols, K=128 ----------------
        int node0 = (blockIdx.x - NBLK_FILL) * 64;
        float4 vx[8];
#pragma unroll
        for (int it = 0; it < 8; it++) {
            int idx = it * 256 + t;                  // 0..2047 float4s of x tile
            int row = idx >> 5, c4 = idx & 31;
            int node = node0 + row;
            if (node < NNODES)
                vx[it] = *(const float4*)(x + (size_t)node * INC + c4 * 4);
            else
                vx[it] = make_float4(0.f, 0.f, 0.f, 0.f);
        }
        uint4 vwh[4], vwl[4];
#pragma unroll
        for (int j = 0; j < 4; j++) {
            vwh[j] = *(const uint4*)(wTh + (size_t)(j * 256 + t) * 8);
            vwl[j] = *(const uint4*)(wTl + (size_t)(j * 256 + t) * 8);
        }
        // convert x -> bf16 hi/lo, write LDS swizzled (k ^= (row&7)<<3, elem units)
#pragma unroll
        for (int it = 0; it < 8; it++) {
            int idx = it * 256 + t;
            int row = idx >> 5, c4 = idx & 31;
            ushort4 hi, lo;
            hi.x = f2bf(vx[it].x); lo.x = f2bf(vx[it].x - bf2f(hi.x));
            hi.y = f2bf(vx[it].y); lo.y = f2bf(vx[it].y - bf2f(hi.y));
            hi.z = f2bf(vx[it].z); lo.z = f2bf(vx[it].z - bf2f(hi.z));
            hi.w = f2bf(vx[it].w); lo.w = f2bf(vx[it].w - bf2f(hi.w));
            int ke = (c4 * 4) ^ ((row & 7) << 3);
            *(ushort4*)&s_a[0][row * 128 + ke] = hi;
            *(ushort4*)&s_a[1][row * 128 + ke] = lo;
        }
#pragma unroll
        for (int j = 0; j < 4; j++) {
            int idx = j * 256 + t;                   // ushort8 chunk of wT[64][128]
            int col = idx >> 4, k0 = (idx & 15) * 8;
            int ke = k0 ^ ((col & 7) << 3);
            *(uint4*)&s_b[0][col * 128 + ke] = vwh[j];
            *(uint4*)&s_b[1][col * 128 + ke] = vwl[j];
        }
        __syncthreads();
        int l = t & 63, wv = t >> 6;
        int mr = l & 15, g = l >> 4;
        int arow = wv * 16 + mr;                     // arow&7 == mr&7 (wv*16 % 8 == 0)
        f32x4 acc[4] = {{0.f, 0.f, 0.f, 0.f}, {0.f, 0.f, 0.f, 0.f},
                        {0.f, 0.f, 0.f, 0.f}, {0.f, 0.f, 0.f, 0.f}};
#pragma unroll
        for (int ks = 0; ks < 4; ks++) {
            int k0 = ks * 32 + g * 8;
            int ko = k0 ^ ((mr & 7) << 3);
            bf16x8 ah = *(const bf16x8*)&s_a[0][arow * 128 + ko];
            bf16x8 al = *(const bf16x8*)&s_a[1][arow * 128 + ko];
#pragma unroll
            for (int cb = 0; cb < 4; cb++) {
                int bo = (cb * 16 + mr) * 128 + ko;
                bf16x8 bh = *(const bf16x8*)&s_b[0][bo];
                bf16x8 bl = *(const bf16x8*)&s_b[1][bo];
                acc[cb] = __builtin_amdgcn_mfma_f32_16x16x32_bf16(ah, bh, acc[cb], 0, 0, 0);
                acc[cb] = __builtin_amdgcn_mfma_f32_16x16x32_bf16(ah, bl, acc[cb], 0, 0, 0);
                acc[cb] = __builtin_amdgcn_mfma_f32_16x16x32_bf16(al, bh, acc[cb], 0, 0, 0);
            }
        }
#pragma unroll
        for (int cb = 0; cb < 4; cb++) {
            int col = cb * 16 + mr;
            float bb = b[col];
#pragma unroll
            for (int r = 0; r < 4; r++) {
                int node = node0 + wv * 16 + g * 4 + r;
                if (node < NNODES)
                    out[(size_t)node * 64 + col] = f2bf(acc[cb][r] + bb);
            }
        }
    }
}

// fill pass 2: one WG per 128-node bucket, fixed csr region [b*CAPE, ...).
// Rows padded to x8 with sentinel n_nodes (points at the zero row).
// csr_src stores BYTE offsets (s*128) of the 128-B bufA rows.
__global__ __launch_bounds__(256) void fill2_kernel(
        const int* __restrict__ bucket_fill, const unsigned int* __restrict__ staging,
        int* __restrict__ csr_src, int* __restrict__ row_start,
        int* __restrict__ row_pdeg, float* __restrict__ norm, int n_nodes) {
    __shared__ int cnt[128];
    __shared__ int dcount[128];
    __shared__ int off[128];
    __shared__ int pscan[128];
    __shared__ unsigned short rank16[CAP];   // 8 KB
    __shared__ unsigned int ht[HSLOTS];      // 16 KB
    int t = threadIdx.x;
    int b = blockIdx.x;
    int node0 = b << BSHIFT;
    int nn = min(128, n_nodes - node0);
    if (t < 128) { cnt[t] = 0; dcount[t] = 0; }
    {
        uint4* h4 = (uint4*)ht;
        uint4 ff = make_uint4(0xFFFFFFFFu, 0xFFFFFFFFu, 0xFFFFFFFFu, 0xFFFFFFFFu);
        for (int i = t; i < HSLOTS / 4; i += 256) h4[i] = ff;
    }
    __syncthreads();
    int start = b << 12;
    int total = bucket_fill[b];
    // phase A: count + rank + dedup
    for (int li = t; li < total; li += 256) {
        unsigned int w = staging[start + li];
        int s = (int)(w & 0x1FFFFu);
        int dl = (int)(w >> 17);
        int r = atomicAdd(&cnt[dl], 1);
        rank16[li] = (unsigned short)r;
        if (s != node0 + dl) {  // self-loops merge with the I-diagonal
            unsigned int slot = ((w * 2654435761u) >> 13) & (HSLOTS - 1);
            while (true) {
                unsigned int prev = atomicCAS(&ht[slot], 0xFFFFFFFFu, w);
                if (prev == 0xFFFFFFFFu) { atomicAdd(&dcount[dl], 1); break; }
                if (prev == w) break;
                slot = (slot + 1) & (HSLOTS - 1);
            }
        }
    }
    __syncthreads();
    // exclusive prefix of x8-padded counts -> csr offsets within [b*CAPE, ...)
    int cv = 0, pv = 0;
    if (t < 128) {
        cv = cnt[t];
        pv = (cv + 7) & ~7;
        pscan[t] = pv;
    }
    __syncthreads();
    for (int o = 1; o < 128; o <<= 1) {
        int xx = (t >= o && t < 128) ? pscan[t - o] : 0;
        __syncthreads();
        if (t < 128) pscan[t] += xx;
        __syncthreads();
    }
    if (t < 128) off[t] = b * CAPE + pscan[t] - pv;
    __syncthreads();
    if (t < nn) {
        row_start[node0 + t] = off[t];
        row_pdeg[node0 + t] = pv;
        norm[node0 + t] = 1.0f / (1.0f + (float)dcount[t]);
    }
    // sentinel-pad the tail of each row (byte offset of the zero row)
    if (t < 128)
        for (int k = cv; k < pv; k++) csr_src[off[t] + k] = n_nodes << 7;
    // phase B: scatter csr (byte offsets: s*128)
    for (int li = t; li < total; li += 256) {
        unsigned int w = staging[start + li];
        int s = (int)(w & 0x1FFFFu);
        int dl = (int)(w >> 17);
        csr_src[off[dl] + (int)rank16[li]] = s << 7;
    }
}

// Four nodes per wave: lanes 0-31 own nodes {4q, 4q+1}, lanes 32-63 own
// {4q+2, 4q+3}. Two independent edge streams (X=even node, Y=odd node) per
// half, each keeping the proven wd0/wd1 edge-pairing -> MLP=4 dword gathers
// in flight at the same ~4 VALU/edge. Each dword wave-load still fetches
// exactly 2 full 128-B h1 rows. 100000 = 4*25000: grid exact, no guards.
// csr holds pre-shifted byte offsets (1 v_add addressing); tail slots clamp
// to the sentinel zero row (L1-resident). Fused PAN combine + relu + rank-4
// projection -> u; h1 never hits global memory.
__global__ void agg_h_kernel(const unsigned int* __restrict__ lin32,
                             const int* __restrict__ row_start,
                             const int* __restrict__ row_pdeg,
                             const int* __restrict__ csr_src,
                             const float* __restrict__ norm,
                             const float* __restrict__ wpan, const float* __restrict__ w44,
                             const float* __restrict__ bias4, float* __restrict__ u,
                             int n_nodes) {
    int t = threadIdx.x;
    int lane = t & 63;
    int sl = lane & 31;                      // channel dword / edge slot
    int h5 = lane >> 5;                      // half: owns nodes 4q+2*h5 + {0,1}
    int quad = blockIdx.x * 4 + (t >> 6);
    if (blockIdx.x == 0 && t < 4) u[n_nodes * 4 + t] = 0.0f;  // zero row for agg_pq4 pads
    int nX = quad * 4 + h5 * 2;
    int nY = nX + 1;
    int e0X = row_start[nX], pdX = row_pdeg[nX];
    int e0Y = row_start[nY], pdY = row_pdeg[nY];
    int pm = max(pdX, pdY);
    int pmax = max(pm, __shfl_xor(pm, 32));  // wave-uniform chunk bound
    int sentB = n_nodes << 7;                // byte offset of the zero row
    unsigned sl4 = (unsigned)sl * 4;
    const char* base8 = (const char*)lin32;
    float xL0 = 0.f, xH0 = 0.f, xL1 = 0.f, xH1 = 0.f;
    float yL0 = 0.f, yH0 = 0.f, yL1 = 0.f, yH1 = 0.f;
    for (int base = 0; base < pmax; base += 32) {
        int li = base + sl;
        int soX = (li < pdX) ? csr_src[e0X + li] : sentB;
        int soY = (li < pdY) ? csr_src[e0Y + li] : sentB;
        int m = min(32, pmax - base);        // wave-uniform, multiple of 8
#pragma unroll
        for (int i = 0; i < 32; i += 2) {
            if (i < m) {
                int xA0 = __builtin_amdgcn_readlane(soX, i);
                int xB0 = __builtin_amdgcn_readlane(soX, 32 + i);
                int xA1 = __builtin_amdgcn_readlane(soX, i + 1);
                int xB1 = __builtin_amdgcn_readlane(soX, 33 + i);
                int yA0 = __builtin_amdgcn_readlane(soY, i);
                int yB0 = __builtin_amdgcn_readlane(soY, 32 + i);
                int yA1 = __builtin_amdgcn_readlane(soY, i + 1);
                int yB1 = __builtin_amdgcn_readlane(soY, 33 + i);
                int ox0 = h5 ? xB0 : xA0;
                int ox1 = h5 ? xB1 : xA1;
                int oy0 = h5 ? yB0 : yA0;
                int oy1 = h5 ? yB1 : yA1;
                unsigned int wx0 = *(const unsigned int*)(base8 + (unsigned)(ox0 + sl4));
                unsigned int wx1 = *(const unsigned int*)(base8 + (unsigned)(ox1 + sl4));
                unsigned int wy0 = *(const unsigned int*)(base8 + (unsigned)(oy0 + sl4));
                unsigned int wy1 = *(const unsigned int*)(base8 + (unsigned)(oy1 + sl4));
                xL0 += __uint_as_float(wx0 << 16);
                xH0 += __uint_as_float(wx0 & 0xFFFF0000u);
                xL1 += __uint_as_float(wx1 << 16);
                xH1 += __uint_as_float(wx1 & 0xFFFF0000u);
                yL0 += __uint_as_float(wy0 << 16);
                yH0 += __uint_as_float(wy0 & 0xFFFF0000u);
                yL1 += __uint_as_float(wy1 << 16);
                yH1 += __uint_as_float(wy1 & 0xFFFF0000u);
            }
        }
    }
    float aLX = xL0 + xL1, aHX = xH0 + xH1;
    float aLY = yL0 + yL1, aHY = yH0 + yH1;
    // self rows: 32 consecutive dwords per half -> coalesced
    unsigned int wsX = *(const unsigned int*)(base8 + (unsigned)((nX << 7) + sl4));
    unsigned int wsY = *(const unsigned int*)(base8 + (unsigned)((nY << 7) + sl4));
    float nrX = norm[nX], nrY = norm[nY];
    float w0 = wpan[0];
    float w01 = wpan[0] * wpan[1];
    float vLX = fmaxf(nrX * (w0 * __uint_as_float(wsX << 16) + w01 * aLX), 0.0f);
    float vHX = fmaxf(nrX * (w0 * __uint_as_float(wsX & 0xFFFF0000u) + w01 * aHX), 0.0f);
    float vLY = fmaxf(nrY * (w0 * __uint_as_float(wsY << 16) + w01 * aLY), 0.0f);
    float vHY = fmaxf(nrY * (w0 * __uint_as_float(wsY & 0xFFFF0000u) + w01 * aHY), 0.0f);
    int c0 = 2 * sl;
    float4 wv0 = *(const float4*)(w44 + c0 * 4);
    float4 wv1 = *(const float4*)(w44 + (c0 + 1) * 4);
    float pX0 = vLX * wv0.x + vHX * wv1.x;
    float pX1 = vLX * wv0.y + vHX * wv1.y;
    float pX2 = vLX * wv0.z + vHX * wv1.z;
    float pX3 = vLX * wv0.w + vHX * wv1.w;
    float pY0 = vLY * wv0.x + vHY * wv1.x;
    float pY1 = vLY * wv0.y + vHY * wv1.y;
    float pY2 = vLY * wv0.z + vHY * wv1.z;
    float pY3 = vLY * wv0.w + vHY * wv1.w;
    for (int off = 16; off; off >>= 1) {     // reduce within the 32-lane half
        pX0 += __shfl_xor(pX0, off);
        pX1 += __shfl_xor(pX1, off);
        pX2 += __shfl_xor(pX2, off);
        pX3 += __shfl_xor(pX3, off);
        pY0 += __shfl_xor(pY0, off);
        pY1 += __shfl_xor(pY1, off);
        pY2 += __shfl_xor(pY2, off);
        pY3 += __shfl_xor(pY3, off);
    }
    if (sl == 0) {                           // lanes 0/32 write node X
        float4 bb = *(const float4*)bias4;
        *(float4*)(u + nX * 4) =
            make_float4(pX0 + bb.x, pX1 + bb.y, pX2 + bb.z, pX3 + bb.w);
    }
    if (sl == 1) {                           // lanes 1/33 write node Y
        float4 bb = *(const float4*)bias4;
        *(float4*)(u + nY * 4) =
            make_float4(pY0 + bb.x, pY1 + bb.y, pY2 + bb.z, pY3 + bb.w);
    }
}

// Layer-2 aggregate on the rank-4 table (x8-padded rows, branch-free):
// pq[n,j] = norm*(w0*u[n,j] + w01*sum u[src,j]).  csr holds s*128 byte offsets;
// u row start (float index) = s*4 = offset>>5.
__global__ void agg_pq4_kernel(const float* __restrict__ u, const int* __restrict__ row_start,
                               const int* __restrict__ row_pdeg,
                               const int* __restrict__ csr_src,
                               const float* __restrict__ norm,
                               const float* __restrict__ wpan, float* __restrict__ pq,
                               int n_nodes) {
    int t = threadIdx.x;
    int node = blockIdx.x * 64 + (t >> 2);
    int j = t & 3;
    if (node >= n_nodes) return;
    int e0 = row_start[node];
    int pd = row_pdeg[node];
    float acc = 0.0f;
    for (int e = 0; e < pd; e += 8) {
#pragma unroll
        for (int k = 0; k < 8; k++) {
            int so = csr_src[e0 + e + k];
            acc += u[(so >> 5) + j];
        }
    }
    float w0 = wpan[0];
    float w01 = wpan[0] * wpan[1];
    pq[node * 4 + j] = norm[node] * (w0 * u[node * 4 + j] + w01 * acc);
}

__global__ void edge_out_kernel(const int* __restrict__ src, const int* __restrict__ dst,
                                const float* __restrict__ pq, const float* __restrict__ bc,
                                float* __restrict__ out, int n_edges) {
    int e = blockIdx.x * blockDim.x + threadIdx.x;
    if (e >= n_edges) return;
    int r = src[e], c = dst[e];
    float2 p = *(const float2*)(pq + r * 4);
    float2 q = *(const float2*)(pq + c * 4 + 2);
    float2 o = make_float2(p.x + q.x + bc[0], p.y + q.y + bc[1]);
    *(float2*)(out + e * 2) = o;
}

extern "C" void kernel_launch(void* const* d_in, const int* in_sizes, int n_in,
                              void* d_out, int out_size, void* d_ws, size_t ws_size,
                              hipStream_t stream) {
    const float* x      = (const float*)d_in[0];
    const int*   eidx   = (const int*)d_in[1];
    const float* w1_lin = (const float*)d_in[2];
    const float* b1_lin = (const float*)d_in[3];
    const float* w1_pan = (const float*)d_in[4];
    const float* w2_lin = (const float*)d_in[5];
    const float* b2_lin = (const float*)d_in[6];
    const float* w2_pan = (const float*)d_in[7];
    const float* wc     = (const float*)d_in[8];
    const float* bc     = (const float*)d_in[9];
    float* out = (float*)d_out;

    const int* src = eidx;           // edge_index[0]
    const int* dst = eidx + NEDGES;  // edge_index[1]

    // ---- workspace carve-up (all 256B-aligned) ----
    char* ws = (char*)d_ws;
    size_t off = 0;
    auto carve = [&](size_t bytes) {
        char* p = ws + off;
        off = (off + bytes + 255) & ~(size_t)255;
        return p;
    };
    int*   bucket_fill = (int*)carve((size_t)NB * 4);
    int*   row_start = (int*)carve((size_t)NNODES * 4);
    int*   row_pdeg  = (int*)carve((size_t)NNODES * 4);
    unsigned int* staging = (unsigned int*)carve((size_t)NB * CAP * 4);   // 12.8 MB
    int*   csr_src  = (int*)carve(((size_t)NB * CAPE + 256) * 4);         // 12.8 MB + slack
    float* nrm      = (float*)carve((size_t)NNODES * 4);
    unsigned short* bufA = (unsigned short*)carve((size_t)(NNODES + 1) * HIDC * 2);
    float* u        = (float*)carve((size_t)(NNODES + 1) * 4 * 4);
    float* pq       = (float*)carve((size_t)NNODES * 4 * 4);
    float* w44      = (float*)carve((size_t)64 * 4 * 4);
    float* bias4    = (float*)carve((size_t)4 * 4);
    unsigned short* wTh = (unsigned short*)carve((size_t)HIDC * INC * 2); // 16 KB
    unsigned short* wTl = (unsigned short*)carve((size_t)HIDC * INC * 2); // 16 KB
    (void)ws_size; (void)in_sizes; (void)n_in; (void)out_size;

    hipMemsetAsync(bucket_fill, 0, (size_t)NB * 4, stream);

    // prep: wT bf16 hi/lo split + w44/bias4 fold + bufA sentinel row
    prep_w_kernel<<<32, 256, 0, stream>>>(w1_lin, wTh, wTl, w2_lin, b2_lin, wc,
                                          w44, bias4, bufA);

    // fat kernel: edge binning (first 391 blocks) || layer-1 MFMA GEMM
    fat_kernel<<<NBLK_FILL + NBLK_LIN, 256, 0, stream>>>(
        x, wTh, wTl, b1_lin, bufA, src, dst, bucket_fill, staging);

    // CSR build pass 2: x8-padded rows + row_start/pdeg + dedup + norm + scatter
    fill2_kernel<<<NB, 256, 0, stream>>>(bucket_fill, staging, csr_src, row_start, row_pdeg,
                                         nrm, NNODES);

    // layer 1 aggregate+relu fused with rank-4 projection -> u (4 nodes/wave)
    agg_h_kernel<<<(NNODES / 16), 256, 0, stream>>>(
        (const unsigned int*)bufA, row_start, row_pdeg, csr_src, nrm, w1_pan, w44, bias4,
        u, NNODES);

    // layer 2 aggregate on the rank-4 table
    agg_pq4_kernel<<<(NNODES + 63) / 64, 256, 0, stream>>>(
        u, row_start, row_pdeg, csr_src, nrm, w2_pan, pq, NNODES);

    // edge head: out[e] = p[src[e]] + q[dst[e]] + bc
    edge_out_kernel<<<NEDGES / 256, 256, 0, stream>>>(src, dst, pq, bc, out, NEDGES);
}